// Round 3
// baseline (257.467 us; speedup 1.0000x reference)
//
#include <hip/hip_runtime.h>
#include <hip/hip_bf16.h>

// GegenbauerKAN == GEMM  y[b,o] = sum_k G[b,k] * Wt[o,k],  M=16384 N=512 K=4096.
// ALPHA=1 => Chebyshev-U: C_{n+1} = 2t*C_n - C_{n-1}, t = tanh(x).
// R3: LDS-free, barrier-free. A-frags computed per-lane in registers (one
// chain == one 8-deg k-group == exactly one MFMA A k-slice); B-frags loaded
// directly from a bf16 [o][k]-layout copy of coeffs in d_ws (L2-resident).
// k-order chosen so each lane's 2 chains per (tm,iter) come from one float2:
//   k = q*8 + d,  i(q) = (q & ~7) | ((q&3)<<1) | ((q>>2)&1)
//   => chain at (it, kc, fq) uses x column it*8 + 2*fq + kc.

#define I_DIM 512
#define O_DIM 512
#define NDEG 8
#define K_DIM (I_DIM * NDEG)                      // 4096
#define W_BYTES ((size_t)O_DIM * K_DIM * sizeof(unsigned short))   // 4 MiB

typedef short s8v __attribute__((ext_vector_type(8)));   // MFMA A/B frag
typedef float f32x4 __attribute__((ext_vector_type(4))); // MFMA C/D frag
typedef unsigned short u16;

__device__ __forceinline__ unsigned pack2bf_rne(float a, float b) {
    unsigned ua = __float_as_uint(a), ub = __float_as_uint(b);
    ua += 0x7fffu + ((ua >> 16) & 1u);
    ub += 0x7fffu + ((ub >> 16) & 1u);
    return (ua >> 16) | (ub & 0xffff0000u);
}

__device__ __forceinline__ float fast_tanh(float v) {
    float e = __expf(v + v);
    float r = __builtin_amdgcn_rcpf(e + 1.0f);
    return 1.0f - (r + r);
}

// one Chebyshev-U chain -> one A fragment (degrees 0..7, bf16 RNE)
__device__ __forceinline__ s8v cheb_frag(float t) {
    const float t2 = t + t;
    const float c1 = t2;
    const float c2 = t2 * c1 - 1.0f;
    const float c3 = t2 * c2 - c1;
    const float c4 = t2 * c3 - c2;
    const float c5 = t2 * c4 - c3;
    const float c6 = t2 * c5 - c4;
    const float c7 = t2 * c6 - c5;
    union { s8v s; __hip_bfloat162 h[4]; } pk;
    pk.h[0] = __float22bfloat162_rn(make_float2(1.0f, c1));
    pk.h[1] = __float22bfloat162_rn(make_float2(c2, c3));
    pk.h[2] = __float22bfloat162_rn(make_float2(c4, c5));
    pk.h[3] = __float22bfloat162_rn(make_float2(c6, c7));
    return pk.s;
}

// coeffs fp32 [i][o][d]  ->  bf16 Wt [o][k],  k = q*8+d with the i(q) permutation
extern "C" __global__ __launch_bounds__(256)
void cvt_w(const float* __restrict__ cf, u16* __restrict__ wt) {
    const int idx = blockIdx.x * 256 + threadIdx.x;   // 0 .. 512*512-1
    const int q = idx & (I_DIM - 1);
    const int o = idx >> 9;
    const int i = (q & ~7) | ((q & 3) << 1) | ((q >> 2) & 1);
    const float* src = cf + ((size_t)i * O_DIM + o) * NDEG;
    const float4 w0 = reinterpret_cast<const float4*>(src)[0];
    const float4 w1 = reinterpret_cast<const float4*>(src)[1];
    union { s8v s; unsigned u[4]; } pk;
    pk.u[0] = pack2bf_rne(w0.x, w0.y);
    pk.u[1] = pack2bf_rne(w0.z, w0.w);
    pk.u[2] = pack2bf_rne(w1.x, w1.y);
    pk.u[3] = pack2bf_rne(w1.z, w1.w);
    *reinterpret_cast<s8v*>(wt + (size_t)o * K_DIM + q * NDEG) = pk.s;
}

template <bool PRECONV>
__global__ __launch_bounds__(256, 2)
void gegen_gemm(const float* __restrict__ x,
                const float* __restrict__ cf,
                const u16* __restrict__ wt,
                float* __restrict__ out)
{
    const int tid  = threadIdx.x;
    const int lane = tid & 63;
    const int wave = tid >> 6;             // 4 waves, stacked in M (share B in L1)
    const int fm   = lane & 15;
    const int fq   = lane >> 4;

    const int m0 = blockIdx.y * 256 + wave * 64;
    const int n0 = blockIdx.x * 64;

    // per-lane base pointers
    const float* xb[4];
#pragma unroll
    for (int tm = 0; tm < 4; ++tm)
        xb[tm] = x + (size_t)(m0 + tm * 16 + fm) * I_DIM + 2 * fq;
    const u16* wb[4];
    const float* cb[4];
#pragma unroll
    for (int tn = 0; tn < 4; ++tn) {
        wb[tn] = wt + (size_t)(n0 + tn * 16 + fm) * K_DIM + fq * NDEG;
        cb[tn] = cf + (size_t)(n0 + tn * 16 + fm) * NDEG;
    }

    f32x4 acc[4][4];
#pragma unroll
    for (int a = 0; a < 4; ++a)
#pragma unroll
        for (int b = 0; b < 4; ++b)
            acc[a][b] = (f32x4){0.0f, 0.0f, 0.0f, 0.0f};

    float2 xv[4];
    s8v    bfr[2][4];

    // ---- prologue loads (iter 0) ----
#pragma unroll
    for (int tm = 0; tm < 4; ++tm)
        xv[tm] = *reinterpret_cast<const float2*>(xb[tm]);
#pragma unroll
    for (int kc = 0; kc < 2; ++kc)
#pragma unroll
        for (int tn = 0; tn < 4; ++tn) {
            if (PRECONV) {
                bfr[kc][tn] = *reinterpret_cast<const s8v*>(wb[tn] + kc * 32);
            } else {
                const int i = 2 * fq + kc;
                const float* p = cb[tn] + (size_t)i * O_DIM * NDEG;
                const float4 w0 = reinterpret_cast<const float4*>(p)[0];
                const float4 w1 = reinterpret_cast<const float4*>(p)[1];
                union { s8v s; unsigned u[4]; } pk;
                pk.u[0] = pack2bf_rne(w0.x, w0.y);
                pk.u[1] = pack2bf_rne(w0.z, w0.w);
                pk.u[2] = pack2bf_rne(w1.x, w1.y);
                pk.u[3] = pack2bf_rne(w1.z, w1.w);
                bfr[kc][tn] = pk.s;
            }
        }

    for (int it = 0; it < K_DIM / 64; ++it) {
        // ---- software-pipelined loads for it+1 ----
        float2 xn[4];
        s8v    bn[2][4];
        if (it < K_DIM / 64 - 1) {
            const int nit = it + 1;
#pragma unroll
            for (int tm = 0; tm < 4; ++tm)
                xn[tm] = *reinterpret_cast<const float2*>(xb[tm] + nit * NDEG);
#pragma unroll
            for (int kc = 0; kc < 2; ++kc)
#pragma unroll
                for (int tn = 0; tn < 4; ++tn) {
                    if (PRECONV) {
                        bn[kc][tn] = *reinterpret_cast<const s8v*>(wb[tn] + nit * 64 + kc * 32);
                    } else {
                        const int i = nit * NDEG + 2 * fq + kc;
                        const float* p = cb[tn] + (size_t)i * O_DIM * NDEG;
                        const float4 w0 = reinterpret_cast<const float4*>(p)[0];
                        const float4 w1 = reinterpret_cast<const float4*>(p)[1];
                        union { s8v s; unsigned u[4]; } pk;
                        pk.u[0] = pack2bf_rne(w0.x, w0.y);
                        pk.u[1] = pack2bf_rne(w0.z, w0.w);
                        pk.u[2] = pack2bf_rne(w1.x, w1.y);
                        pk.u[3] = pack2bf_rne(w1.z, w1.w);
                        bn[kc][tn] = pk.s;
                    }
                }
        }

        // ---- compute iter it: chains -> A frags -> 32 MFMA ----
#pragma unroll
        for (int kc = 0; kc < 2; ++kc) {
            s8v afr[4];
#pragma unroll
            for (int tm = 0; tm < 4; ++tm)
                afr[tm] = cheb_frag(fast_tanh(kc ? xv[tm].y : xv[tm].x));
#pragma unroll
            for (int tm = 0; tm < 4; ++tm)
#pragma unroll
                for (int tn = 0; tn < 4; ++tn)
                    acc[tm][tn] = __builtin_amdgcn_mfma_f32_16x16x32_bf16(
                        afr[tm], bfr[kc][tn], acc[tm][tn], 0, 0, 0);
        }

#pragma unroll
        for (int tm = 0; tm < 4; ++tm) xv[tm] = xn[tm];
#pragma unroll
        for (int kc = 0; kc < 2; ++kc)
#pragma unroll
            for (int tn = 0; tn < 4; ++tn) bfr[kc][tn] = bn[kc][tn];
    }

    // ---- epilogue: C/D col=fm, row=fq*4+r ----
#pragma unroll
    for (int tm = 0; tm < 4; ++tm)
#pragma unroll
        for (int tn = 0; tn < 4; ++tn) {
            const int row = m0 + tm * 16 + fq * 4;
            const int col = n0 + tn * 16 + fm;
#pragma unroll
            for (int r = 0; r < 4; ++r)
                out[(size_t)(row + r) * O_DIM + col] = acc[tm][tn][r];
        }
}

extern "C" void kernel_launch(void* const* d_in, const int* in_sizes, int n_in,
                              void* d_out, int out_size, void* d_ws, size_t ws_size,
                              hipStream_t stream) {
    const float* x  = (const float*)d_in[0];
    const float* cf = (const float*)d_in[1];
    float* out = (float*)d_out;
    const int M = in_sizes[0] / I_DIM;                 // 16384
    dim3 grid(O_DIM / 64, M / 256);                    // (8, 64) = 512 blocks, 2048 waves
    dim3 block(256, 1, 1);

    if (ws_size >= W_BYTES) {
        u16* wt = (u16*)d_ws;
        cvt_w<<<(I_DIM * O_DIM) / 256, 256, 0, stream>>>(cf, wt);
        gegen_gemm<true><<<grid, block, 0, stream>>>(x, cf, wt, out);
    } else {
        gegen_gemm<false><<<grid, block, 0, stream>>>(x, cf, nullptr, out);
    }
}

// Round 4
// 200.631 us; speedup vs baseline: 1.2833x; 1.2833x over previous
//
#include <hip/hip_runtime.h>
#include <hip/hip_bf16.h>

// GegenbauerKAN == GEMM y[b,o] = sum_k G[b,k]*W[k,o], M=16384 N=512 K=4096.
// ALPHA=1 => Chebyshev-U: C_{n+1} = 2t*C_n - C_{n-1}, t = tanh(x).
// R4 hybrid: A-frags computed per-lane in registers (VALU pipe), B staged
// fp32->bf16 into double-buffered LDS with 64B/thread coalesced loads (LDS
// pipe), MFMA pipe is the roof. Single kernel, no workspace, 1 barrier/iter.
// k-order: slot s=kc*4+fq holds i = it*8 + 2*fq + kc, so each lane's two
// chains per (tm,iter) come from one float2 x-load.

#define I_DIM 512
#define O_DIM 512
#define NDEG 8
#define KIT 64            // K iterations, 8 i-values each
#define LSTR 72           // Ws row stride in bf16 (144 B; breaks pow-2 banking)

typedef short s8v __attribute__((ext_vector_type(8)));    // MFMA A/B frag
typedef float f32x4 __attribute__((ext_vector_type(4)));  // MFMA C/D frag
typedef unsigned short u16;

__device__ __forceinline__ unsigned pack2bf_rne(float a, float b) {
    unsigned ua = __float_as_uint(a), ub = __float_as_uint(b);
    ua += 0x7fffu + ((ua >> 16) & 1u);
    ub += 0x7fffu + ((ub >> 16) & 1u);
    return (ua >> 16) | (ub & 0xffff0000u);
}

__device__ __forceinline__ float fast_tanh(float v) {
    float e = __expf(v + v);
    float r = __builtin_amdgcn_rcpf(e + 1.0f);
    return 1.0f - (r + r);
}

// Chebyshev-U chain (degrees 0..7) -> one MFMA A-fragment, bf16 RNE
__device__ __forceinline__ s8v cheb_frag(float t) {
    const float t2 = t + t;
    const float c1 = t2;
    const float c2 = t2 * c1 - 1.0f;
    const float c3 = t2 * c2 - c1;
    const float c4 = t2 * c3 - c2;
    const float c5 = t2 * c4 - c3;
    const float c6 = t2 * c5 - c4;
    const float c7 = t2 * c6 - c5;
    union { s8v s; unsigned u[4]; } pk;
    pk.u[0] = pack2bf_rne(1.0f, c1);
    pk.u[1] = pack2bf_rne(c2, c3);
    pk.u[2] = pack2bf_rne(c4, c5);
    pk.u[3] = pack2bf_rne(c6, c7);
    return pk.s;
}

__global__ __launch_bounds__(256, 2)
void gegen_gemm(const float* __restrict__ x,
                const float* __restrict__ cf,
                float* __restrict__ out)
{
    // B tile: 64 o-rows x 64 k (8 slots * 8 deg), double-buffered, padded
    __shared__ u16 Ws[2][64 * LSTR];

    const int tid  = threadIdx.x;
    const int lane = tid & 63;
    const int wave = tid >> 6;            // 4 waves stacked in M
    const int fm   = lane & 15;
    const int fq   = lane >> 4;

    const int m0 = blockIdx.y * 256 + wave * 64;
    const int n0 = blockIdx.x * 64;

    // ---- W staging map: thread -> (slot s, o-pair); 64 B contiguous per thread
    const int s  = tid >> 5;              // 0..7
    const int ol = (tid & 31) << 1;       // 0,2,..,62
    const int ig = 2 * (s & 3) + (s >> 2);   // i offset within 8-group for slot s
    const float* wp = cf + ((size_t)ig * O_DIM + n0 + ol) * NDEG;  // 16 floats
    u16* wd0 = &Ws[0][ol * LSTR + s * NDEG];
    u16* wd1 = &Ws[0][(ol + 1) * LSTR + s * NDEG];

    // ---- x pointers: lane (fm,fq) covers rows m0+tm*16+fm, cols 2fq,2fq+1
    const float* xb[4];
#pragma unroll
    for (int tm = 0; tm < 4; ++tm)
        xb[tm] = x + (size_t)(m0 + tm * 16 + fm) * I_DIM + 2 * fq;

    f32x4 acc[4][4];
#pragma unroll
    for (int a = 0; a < 4; ++a)
#pragma unroll
        for (int b = 0; b < 4; ++b)
            acc[a][b] = (f32x4){0.0f, 0.0f, 0.0f, 0.0f};

    // ---- prologue loads (iter 0)
    float4 wv0 = reinterpret_cast<const float4*>(wp)[0];
    float4 wv1 = reinterpret_cast<const float4*>(wp)[1];
    float4 wv2 = reinterpret_cast<const float4*>(wp)[2];
    float4 wv3 = reinterpret_cast<const float4*>(wp)[3];
    float2 xv[4];
#pragma unroll
    for (int tm = 0; tm < 4; ++tm)
        xv[tm] = *reinterpret_cast<const float2*>(xb[tm]);

    for (int it = 0; it < KIT; ++it) {
        const int pbuf = (it & 1) * (64 * LSTR);

        // ---- convert & store this iter's W tile (data loaded last iter)
        {
            union { s8v s; unsigned u[4]; } pa, pb;
            pa.u[0] = pack2bf_rne(wv0.x, wv0.y);
            pa.u[1] = pack2bf_rne(wv0.z, wv0.w);
            pa.u[2] = pack2bf_rne(wv1.x, wv1.y);
            pa.u[3] = pack2bf_rne(wv1.z, wv1.w);
            pb.u[0] = pack2bf_rne(wv2.x, wv2.y);
            pb.u[1] = pack2bf_rne(wv2.z, wv2.w);
            pb.u[2] = pack2bf_rne(wv3.x, wv3.y);
            pb.u[3] = pack2bf_rne(wv3.z, wv3.w);
            *reinterpret_cast<s8v*>(wd0 + pbuf) = pa.s;
            *reinterpret_cast<s8v*>(wd1 + pbuf) = pb.s;
        }
        __syncthreads();

        // ---- prefetch next tiles AFTER the barrier: their vmcnt drain
        // happens at the NEXT barrier, hidden behind this iter's compute.
        float4 wn0, wn1, wn2, wn3;
        float2 xn[4];
        if (it < KIT - 1) {
            const float* wsrc = wp + (size_t)(it + 1) * (NDEG * O_DIM * NDEG);
            wn0 = reinterpret_cast<const float4*>(wsrc)[0];
            wn1 = reinterpret_cast<const float4*>(wsrc)[1];
            wn2 = reinterpret_cast<const float4*>(wsrc)[2];
            wn3 = reinterpret_cast<const float4*>(wsrc)[3];
#pragma unroll
            for (int tm = 0; tm < 4; ++tm)
                xn[tm] = *reinterpret_cast<const float2*>(xb[tm] + (it + 1) * NDEG);
        }

        // ---- compute: chains (VALU) -> A frags; B frags from LDS; 32 MFMA
#pragma unroll
        for (int kc = 0; kc < 2; ++kc) {
            s8v afr[4];
#pragma unroll
            for (int tm = 0; tm < 4; ++tm)
                afr[tm] = cheb_frag(fast_tanh(kc ? xv[tm].y : xv[tm].x));
            s8v bfr[4];
#pragma unroll
            for (int tn = 0; tn < 4; ++tn)
                bfr[tn] = *reinterpret_cast<const s8v*>(
                    &Ws[0][pbuf + (tn * 16 + fm) * LSTR + kc * 32 + fq * NDEG]);
#pragma unroll
            for (int tm = 0; tm < 4; ++tm)
#pragma unroll
                for (int tn = 0; tn < 4; ++tn)
                    acc[tm][tn] = __builtin_amdgcn_mfma_f32_16x16x32_bf16(
                        afr[tm], bfr[tn], acc[tm][tn], 0, 0, 0);
        }

        wv0 = wn0; wv1 = wn1; wv2 = wn2; wv3 = wn3;
#pragma unroll
        for (int tm = 0; tm < 4; ++tm) xv[tm] = xn[tm];
    }

    // ---- epilogue: C/D col=fm, row=fq*4+r
#pragma unroll
    for (int tm = 0; tm < 4; ++tm)
#pragma unroll
        for (int tn = 0; tn < 4; ++tn) {
            const int row = m0 + tm * 16 + fq * 4;
            const int col = n0 + tn * 16 + fm;
#pragma unroll
            for (int r = 0; r < 4; ++r)
                out[(size_t)(row + r) * O_DIM + col] = acc[tm][tn][r];
        }
}

extern "C" void kernel_launch(void* const* d_in, const int* in_sizes, int n_in,
                              void* d_out, int out_size, void* d_ws, size_t ws_size,
                              hipStream_t stream) {
    const float* x  = (const float*)d_in[0];
    const float* cf = (const float*)d_in[1];
    float* out = (float*)d_out;
    const int M = in_sizes[0] / I_DIM;            // 16384
    dim3 grid(O_DIM / 64, M / 256);               // (8, 64) = 512 blocks
    gegen_gemm<<<grid, dim3(256, 1, 1), 0, stream>>>(x, cf, out);
}